// Round 1
// baseline (5632.757 us; speedup 1.0000x reference)
//
#include <hip/hip_runtime.h>

#define BM 64
#define BN 64
#define BK 16

// ---------------- fp32 tiled GEMM: C[M,N] = A[M,K] @ B[K,N] ----------------
// block = 256 threads (16x16), each computes a 4x4 microtile. K,N must be
// multiples of BK/BN (true here: K in {1024,512}, N in {512,256}); M guarded.
__global__ __launch_bounds__(256) void sgemm_tiled(
    const float* __restrict__ A, const float* __restrict__ B,
    float* __restrict__ C, int M, int N, int K) {
  __shared__ float As[BK][BM + 1];
  __shared__ float Bs[BK][BN + 1];
  const int bm = blockIdx.y * BM;
  const int bn = blockIdx.x * BN;
  const int tid = threadIdx.x;
  const int tx = tid & 15;   // n direction
  const int ty = tid >> 4;   // m direction

  float acc[4][4] = {};

  // A-tile load map: 64 rows x 16 k, one float4 per thread
  const int ar = tid >> 2;          // 0..63
  const int ac = (tid & 3) << 2;    // 0,4,8,12
  int arow = bm + ar;
  if (arow >= M) arow = M - 1;      // clamp; OOB rows feed only guarded stores
  // B-tile load map: 16 k x 64 cols, one float4 per thread
  const int br = tid >> 4;          // 0..15
  const int bc = (tid & 15) << 2;   // 0..60

  for (int k0 = 0; k0 < K; k0 += BK) {
    float4 av = *(const float4*)(A + (size_t)arow * K + k0 + ac);
    float4 bv = *(const float4*)(B + (size_t)(k0 + br) * N + bn + bc);
    As[ac + 0][ar] = av.x; As[ac + 1][ar] = av.y;
    As[ac + 2][ar] = av.z; As[ac + 3][ar] = av.w;
    Bs[br][bc + 0] = bv.x; Bs[br][bc + 1] = bv.y;
    Bs[br][bc + 2] = bv.z; Bs[br][bc + 3] = bv.w;
    __syncthreads();
#pragma unroll
    for (int kk = 0; kk < BK; ++kk) {
      float a[4], b[4];
#pragma unroll
      for (int i = 0; i < 4; ++i) a[i] = As[kk][ty * 4 + i];
#pragma unroll
      for (int j = 0; j < 4; ++j) b[j] = Bs[kk][tx * 4 + j];
#pragma unroll
      for (int i = 0; i < 4; ++i)
#pragma unroll
        for (int j = 0; j < 4; ++j) acc[i][j] += a[i] * b[j];
    }
    __syncthreads();
  }
#pragma unroll
  for (int i = 0; i < 4; ++i) {
    int row = bm + ty * 4 + i;
    if (row < M) {
      float4 v = make_float4(acc[i][0], acc[i][1], acc[i][2], acc[i][3]);
      *(float4*)(C + (size_t)row * N + bn + tx * 4) = v;
    }
  }
}

// ------------- edge scatter: agg[dst[e]] += S[src[e]] * w[e] ---------------
// One thread per (edge, float4-group). Consecutive threads share an edge ->
// coalesced gather of S row and coalesced atomic addresses in agg row.
__global__ __launch_bounds__(256) void scatter_add(
    const float* __restrict__ S, const int* __restrict__ src,
    const int* __restrict__ dst, const float* __restrict__ w,
    float* __restrict__ agg, long long total, int gshift, int D) {
  long long idx = (long long)blockIdx.x * blockDim.x + threadIdx.x;
  if (idx >= total) return;
  int e = (int)(idx >> gshift);
  int f = ((int)idx & ((1 << gshift) - 1)) << 2;
  int s = src[e], d = dst[e];
  float ww = w[e];
  float4 v = *(const float4*)(S + (size_t)s * D + f);
  float* o = agg + (size_t)d * D + f;
  atomicAdd(o + 0, v.x * ww);
  atomicAdd(o + 1, v.y * ww);
  atomicAdd(o + 2, v.z * ww);
  atomicAdd(o + 3, v.w * ww);
}

// ---------------- out = relu(in + bias), float4-vectorized ----------------
__global__ __launch_bounds__(256) void bias_relu4(
    const float* __restrict__ in, const float* __restrict__ bias,
    float* __restrict__ out, long long total4, int dmask4) {
  long long idx = (long long)blockIdx.x * blockDim.x + threadIdx.x;
  if (idx >= total4) return;
  int f4 = ((int)idx) & dmask4;  // float4-group index within the row
  float4 v = *(const float4*)(in + idx * 4);
  const float4 b = *(const float4*)(bias + (size_t)f4 * 4);
  v.x = fmaxf(v.x + b.x, 0.f);
  v.y = fmaxf(v.y + b.y, 0.f);
  v.z = fmaxf(v.z + b.z, 0.f);
  v.w = fmaxf(v.w + b.w, 0.f);
  *(float4*)(out + idx * 4) = v;
}

extern "C" void kernel_launch(void* const* d_in, const int* in_sizes, int n_in,
                              void* d_out, int out_size, void* d_ws, size_t ws_size,
                              hipStream_t stream) {
  const float* x  = (const float*)d_in[0];
  const int*   ei = (const int*)d_in[1];
  const float* ew = (const float*)d_in[2];
  const float* W1 = (const float*)d_in[3];
  const float* b1 = (const float*)d_in[4];
  const float* W2 = (const float*)d_in[5];
  const float* b2 = (const float*)d_in[6];

  const int D_IN = 1024, D_HID = 512, D_LAT = 256;
  const int Nn = in_sizes[0] / D_IN;   // 50000
  const int E  = in_sizes[2];          // 400000
  const int* src = ei;                 // edge_index[0]
  const int* dstp = ei + E;            // edge_index[1]

  // workspace layout: [ s1 : Nn*D_HID ][ agg1/h : Nn*D_HID ]   (~204.8 MB)
  float* s1   = (float*)d_ws;
  float* agg1 = s1 + (size_t)Nn * D_HID;
  float* s2   = s1;                 // s1 dead after scatter1 -> reuse
  float* agg2 = (float*)d_out;      // aggregate layer-2 directly into d_out
  float* out  = (float*)d_out;

  // ---- layer 1 ----
  dim3 g1(D_HID / BN, (Nn + BM - 1) / BM);
  sgemm_tiled<<<g1, 256, 0, stream>>>(x, W1, s1, Nn, D_HID, D_IN);

  hipMemsetAsync(agg1, 0, (size_t)Nn * D_HID * sizeof(float), stream);
  long long tot1 = (long long)E * (D_HID / 4);
  scatter_add<<<(int)((tot1 + 255) / 256), 256, 0, stream>>>(
      s1, src, dstp, ew, agg1, tot1, 7, D_HID);

  long long t4a = (long long)Nn * D_HID / 4;
  bias_relu4<<<(int)((t4a + 255) / 256), 256, 0, stream>>>(
      agg1, b1, agg1, t4a, D_HID / 4 - 1);

  // ---- layer 2 ----
  dim3 g2(D_LAT / BN, (Nn + BM - 1) / BM);
  sgemm_tiled<<<g2, 256, 0, stream>>>(agg1, W2, s2, Nn, D_LAT, D_HID);

  hipMemsetAsync(agg2, 0, (size_t)Nn * D_LAT * sizeof(float), stream);
  long long tot2 = (long long)E * (D_LAT / 4);
  scatter_add<<<(int)((tot2 + 255) / 256), 256, 0, stream>>>(
      s2, src, dstp, ew, agg2, tot2, 6, D_LAT);

  long long t4b = (long long)Nn * D_LAT / 4;
  bias_relu4<<<(int)((t4b + 255) / 256), 256, 0, stream>>>(
      agg2, b2, out, t4b, D_LAT / 4 - 1);
}

// Round 2
// 1844.938 us; speedup vs baseline: 3.0531x; 3.0531x over previous
//
#include <hip/hip_runtime.h>

#define BM 64
#define BN 64
#define BK 16

// ---------------- fp32 tiled GEMM: C[M,N] = A[M,K] @ B[K,N] ----------------
__global__ __launch_bounds__(256) void sgemm_tiled(
    const float* __restrict__ A, const float* __restrict__ B,
    float* __restrict__ C, int M, int N, int K) {
  __shared__ float As[BK][BM + 1];
  __shared__ float Bs[BK][BN + 1];
  const int bm = blockIdx.y * BM;
  const int bn = blockIdx.x * BN;
  const int tid = threadIdx.x;
  const int tx = tid & 15;
  const int ty = tid >> 4;

  float acc[4][4] = {};

  const int ar = tid >> 2;
  const int ac = (tid & 3) << 2;
  int arow = bm + ar;
  if (arow >= M) arow = M - 1;
  const int br = tid >> 4;
  const int bc = (tid & 15) << 2;

  for (int k0 = 0; k0 < K; k0 += BK) {
    float4 av = *(const float4*)(A + (size_t)arow * K + k0 + ac);
    float4 bv = *(const float4*)(B + (size_t)(k0 + br) * N + bn + bc);
    As[ac + 0][ar] = av.x; As[ac + 1][ar] = av.y;
    As[ac + 2][ar] = av.z; As[ac + 3][ar] = av.w;
    Bs[br][bc + 0] = bv.x; Bs[br][bc + 1] = bv.y;
    Bs[br][bc + 2] = bv.z; Bs[br][bc + 3] = bv.w;
    __syncthreads();
#pragma unroll
    for (int kk = 0; kk < BK; ++kk) {
      float a[4], b[4];
#pragma unroll
      for (int i = 0; i < 4; ++i) a[i] = As[kk][ty * 4 + i];
#pragma unroll
      for (int j = 0; j < 4; ++j) b[j] = Bs[kk][tx * 4 + j];
#pragma unroll
      for (int i = 0; i < 4; ++i)
#pragma unroll
        for (int j = 0; j < 4; ++j) acc[i][j] += a[i] * b[j];
    }
    __syncthreads();
  }
#pragma unroll
  for (int i = 0; i < 4; ++i) {
    int row = bm + ty * 4 + i;
    if (row < M) {
      float4 v = make_float4(acc[i][0], acc[i][1], acc[i][2], acc[i][3]);
      *(float4*)(C + (size_t)row * N + bn + tx * 4) = v;
    }
  }
}

// ----------------------- CSR build: histogram of dst -----------------------
__global__ __launch_bounds__(256) void hist_dst(
    const int* __restrict__ dst, int* __restrict__ cnt, int E) {
  int e = blockIdx.x * blockDim.x + threadIdx.x;
  if (e < E) atomicAdd(&cnt[dst[e]], 1);
}

// --- single-block scan: rowptr[i+1]=incl_sum(deg), cursor[i]=excl_sum(deg) ---
// deg aliases cursor on entry (in-place safe: chunk reads precede its writes).
__global__ __launch_bounds__(1024) void scan_csr(
    int* __restrict__ cursor, int* __restrict__ rowptr, int n) {
  __shared__ int sm[1024];
  __shared__ int carry_s;
  const int t = threadIdx.x;
  if (t == 0) carry_s = 0;
  __syncthreads();
  for (int base = 0; base < n; base += 1024) {
    const int i = base + t;
    const int v = (i < n) ? cursor[i] : 0;
    sm[t] = v;
    __syncthreads();
    int x = v;
#pragma unroll
    for (int off = 1; off < 1024; off <<= 1) {
      int y = (t >= off) ? sm[t - off] : 0;
      __syncthreads();
      x += y;
      sm[t] = x;
      __syncthreads();
    }
    const int carry = carry_s;
    if (i < n) {
      rowptr[i + 1] = carry + x;   // inclusive
      cursor[i] = carry + x - v;   // exclusive (fill cursor start)
    }
    __syncthreads();
    if (t == 1023) carry_s = carry + x;
    __syncthreads();
  }
  if (t == 0) rowptr[0] = 0;
}

// --------------------- CSR fill: eid sorted by dst bucket -------------------
__global__ __launch_bounds__(256) void fill_csr(
    const int* __restrict__ dst, int* __restrict__ cursor,
    int* __restrict__ eid, int E) {
  int e = blockIdx.x * blockDim.x + threadIdx.x;
  if (e < E) {
    int pos = atomicAdd(&cursor[dst[e]], 1);
    eid[pos] = e;
  }
}

// ---- gather aggregate + bias + relu: out[n] = relu(sum_e w*S[src] + b) ----
// tpn = D/4 threads per node (power of 2); npb = 256/tpn nodes per block.
__global__ __launch_bounds__(256) void gather_agg_bias_relu(
    const float* __restrict__ S, const int* __restrict__ src,
    const float* __restrict__ w, const int* __restrict__ rowptr,
    const int* __restrict__ eid, const float* __restrict__ bias,
    float* __restrict__ out, int Nn, int D, int tpn_shift) {
  const int tpn = 1 << tpn_shift;
  const int tn = threadIdx.x & (tpn - 1);
  const int node = blockIdx.x * (256 >> tpn_shift) + (threadIdx.x >> tpn_shift);
  if (node >= Nn) return;
  const int f = tn << 2;
  const int beg = rowptr[node];
  const int end = rowptr[node + 1];
  float4 acc = make_float4(0.f, 0.f, 0.f, 0.f);
  for (int i = beg; i < end; ++i) {
    const int e = eid[i];
    const int s = src[e];
    const float ww = w[e];
    const float4 v = *(const float4*)(S + (size_t)s * D + f);
    acc.x = fmaf(v.x, ww, acc.x);
    acc.y = fmaf(v.y, ww, acc.y);
    acc.z = fmaf(v.z, ww, acc.z);
    acc.w = fmaf(v.w, ww, acc.w);
  }
  const float4 b = *(const float4*)(bias + f);
  float4 r;
  r.x = fmaxf(acc.x + b.x, 0.f);
  r.y = fmaxf(acc.y + b.y, 0.f);
  r.z = fmaxf(acc.z + b.z, 0.f);
  r.w = fmaxf(acc.w + b.w, 0.f);
  *(float4*)(out + (size_t)node * D + f) = r;
}

// ------------------- fallback (round-1) atomic scatter path -----------------
__global__ __launch_bounds__(256) void scatter_add(
    const float* __restrict__ S, const int* __restrict__ src,
    const int* __restrict__ dst, const float* __restrict__ w,
    float* __restrict__ agg, long long total, int gshift, int D) {
  long long idx = (long long)blockIdx.x * blockDim.x + threadIdx.x;
  if (idx >= total) return;
  int e = (int)(idx >> gshift);
  int f = ((int)idx & ((1 << gshift) - 1)) << 2;
  int s = src[e], d = dst[e];
  float ww = w[e];
  float4 v = *(const float4*)(S + (size_t)s * D + f);
  float* o = agg + (size_t)d * D + f;
  atomicAdd(o + 0, v.x * ww);
  atomicAdd(o + 1, v.y * ww);
  atomicAdd(o + 2, v.z * ww);
  atomicAdd(o + 3, v.w * ww);
}

__global__ __launch_bounds__(256) void bias_relu4(
    const float* __restrict__ in, const float* __restrict__ bias,
    float* __restrict__ out, long long total4, int dmask4) {
  long long idx = (long long)blockIdx.x * blockDim.x + threadIdx.x;
  if (idx >= total4) return;
  int f4 = ((int)idx) & dmask4;
  float4 v = *(const float4*)(in + idx * 4);
  const float4 b = *(const float4*)(bias + (size_t)f4 * 4);
  v.x = fmaxf(v.x + b.x, 0.f);
  v.y = fmaxf(v.y + b.y, 0.f);
  v.z = fmaxf(v.z + b.z, 0.f);
  v.w = fmaxf(v.w + b.w, 0.f);
  *(float4*)(out + idx * 4) = v;
}

extern "C" void kernel_launch(void* const* d_in, const int* in_sizes, int n_in,
                              void* d_out, int out_size, void* d_ws, size_t ws_size,
                              hipStream_t stream) {
  const float* x  = (const float*)d_in[0];
  const int*   ei = (const int*)d_in[1];
  const float* ew = (const float*)d_in[2];
  const float* W1 = (const float*)d_in[3];
  const float* b1 = (const float*)d_in[4];
  const float* W2 = (const float*)d_in[5];
  const float* b2 = (const float*)d_in[6];

  const int D_IN = 1024, D_HID = 512, D_LAT = 256;
  const int Nn = in_sizes[0] / D_IN;   // 50000
  const int E  = in_sizes[2];          // 400000
  const int* src = ei;                 // edge_index[0]
  const int* dstp = ei + E;            // edge_index[1]

  // ws layout: [ s1 : Nn*512 f ][ agg1 : Nn*512 f ][ rowptr ][ cursor ][ eid ]
  float* s1   = (float*)d_ws;
  float* agg1 = s1 + (size_t)Nn * D_HID;
  int* rowptr = (int*)(agg1 + (size_t)Nn * D_HID);
  int* cursor = rowptr + (Nn + 1);
  int* eid    = cursor + Nn;
  float* s2   = s1;                 // s1 dead after gather1 -> reuse
  float* out  = (float*)d_out;

  const size_t needed = (size_t)Nn * D_HID * 2 * sizeof(float)
                      + (size_t)(2 * Nn + 1 + E) * sizeof(int);

  if (ws_size >= needed) {
    // ---------- CSR build (independent of GEMM1, ~0.8M int atomics) ----------
    hipMemsetAsync(cursor, 0, (size_t)Nn * sizeof(int), stream);
    hist_dst<<<(E + 255) / 256, 256, 0, stream>>>(dstp, cursor, E);
    scan_csr<<<1, 1024, 0, stream>>>(cursor, rowptr, Nn);
    fill_csr<<<(E + 255) / 256, 256, 0, stream>>>(dstp, cursor, eid, E);

    // ---- layer 1: GEMM -> gather(+bias+relu) ----
    dim3 g1(D_HID / BN, (Nn + BM - 1) / BM);
    sgemm_tiled<<<g1, 256, 0, stream>>>(x, W1, s1, Nn, D_HID, D_IN);
    {
      const int tpn_shift = 7;               // D=512 -> 128 thr/node, 2 nodes/blk
      const int npb = 256 >> tpn_shift;
      gather_agg_bias_relu<<<(Nn + npb - 1) / npb, 256, 0, stream>>>(
          s1, src, ew, rowptr, eid, b1, agg1, Nn, D_HID, tpn_shift);
    }

    // ---- layer 2: GEMM -> gather(+bias+relu) into d_out ----
    dim3 g2(D_LAT / BN, (Nn + BM - 1) / BM);
    sgemm_tiled<<<g2, 256, 0, stream>>>(agg1, W2, s2, Nn, D_LAT, D_HID);
    {
      const int tpn_shift = 6;               // D=256 -> 64 thr/node, 4 nodes/blk
      const int npb = 256 >> tpn_shift;
      gather_agg_bias_relu<<<(Nn + npb - 1) / npb, 256, 0, stream>>>(
          s2, src, ew, rowptr, eid, b2, out, Nn, D_LAT, tpn_shift);
    }
  } else {
    // ---------------- fallback: round-1 atomic-scatter path ----------------
    dim3 g1(D_HID / BN, (Nn + BM - 1) / BM);
    sgemm_tiled<<<g1, 256, 0, stream>>>(x, W1, s1, Nn, D_HID, D_IN);
    hipMemsetAsync(agg1, 0, (size_t)Nn * D_HID * sizeof(float), stream);
    long long tot1 = (long long)E * (D_HID / 4);
    scatter_add<<<(int)((tot1 + 255) / 256), 256, 0, stream>>>(
        s1, src, dstp, ew, agg1, tot1, 7, D_HID);
    long long t4a = (long long)Nn * D_HID / 4;
    bias_relu4<<<(int)((t4a + 255) / 256), 256, 0, stream>>>(
        agg1, b1, agg1, t4a, D_HID / 4 - 1);

    dim3 g2(D_LAT / BN, (Nn + BM - 1) / BM);
    sgemm_tiled<<<g2, 256, 0, stream>>>(agg1, W2, s2, Nn, D_LAT, D_HID);
    hipMemsetAsync(out, 0, (size_t)Nn * D_LAT * sizeof(float), stream);
    long long tot2 = (long long)E * (D_LAT / 4);
    scatter_add<<<(int)((tot2 + 255) / 256), 256, 0, stream>>>(
        s2, src, dstp, ew, out, tot2, 6, D_LAT);
    long long t4b = (long long)Nn * D_LAT / 4;
    bias_relu4<<<(int)((t4b + 255) / 256), 256, 0, stream>>>(
        out, b2, out, t4b, D_LAT / 4 - 1);
  }
}

// Round 3
// 677.202 us; speedup vs baseline: 8.3177x; 2.7244x over previous
//
#include <hip/hip_runtime.h>

typedef __attribute__((ext_vector_type(8))) short short8;
typedef __attribute__((ext_vector_type(4))) float floatx4;

#define GLOBAL_AS __attribute__((address_space(1)))
#define LDS_AS __attribute__((address_space(3)))

__device__ __forceinline__ void gload_lds16(const void* g, void* l) {
  __builtin_amdgcn_global_load_lds((const GLOBAL_AS unsigned int*)g,
                                   (LDS_AS unsigned int*)l, 16, 0, 0);
}

__device__ __forceinline__ unsigned short rnbf(float f) {
  unsigned int v = __builtin_bit_cast(unsigned int, f);
  return (unsigned short)((v + 0x7fff + ((v >> 16) & 1)) >> 16);
}
__device__ __forceinline__ float bflo(unsigned int u) {
  return __builtin_bit_cast(float, u << 16);
}
__device__ __forceinline__ float bfhi(unsigned int u) {
  return __builtin_bit_cast(float, u & 0xffff0000u);
}

// ================= bf16 MFMA GEMM: C[M,N] = A[M,K] @ Bt[N,K]^T ==============
// 128x128 tile, BK=64, 256 thr = 4 waves in 2x2, each wave 64x64 (4x4 MFMA).
// Staging: global_load_lds width=16 with XOR chunk swizzle: LDS chunk c of
// local row r holds global chunk c^(r&7)  (row = 8 chunks of 16B). Fragment
// ds_read_b128 then lands on bank group (swz*4) -> lanes spread 8 groups.
#define TM 128
#define TN 128
#define BKE 64

__global__ __launch_bounds__(256) void gemm_bf16(
    const unsigned short* __restrict__ A,   // [M,K] bf16
    const unsigned short* __restrict__ Bt,  // [N,K] bf16 (= B^T)
    unsigned short* __restrict__ C,         // [M,N] bf16
    int M, int N, int K) {
  __shared__ __align__(16) unsigned short As[TM * BKE];
  __shared__ __align__(16) unsigned short Bs[TN * BKE];

  const int tid  = threadIdx.x;
  const int wave = tid >> 6;
  const int lane = tid & 63;
  const int wm = wave >> 1, wn = wave & 1;
  const int l15 = lane & 15, quad = lane >> 4;

  const int bm = blockIdx.y * TM;
  const int bn = blockIdx.x * TN;

  floatx4 acc[4][4];
#pragma unroll
  for (int i = 0; i < 4; ++i)
#pragma unroll
    for (int j = 0; j < 4; ++j) acc[i][j] = (floatx4){0.f, 0.f, 0.f, 0.f};

  // per-lane staging descriptors (k0-independent)
  const unsigned short* aptr[4];
  const unsigned short* bptr[4];
  int ldsoff[4];
#pragma unroll
  for (int j = 0; j < 4; ++j) {
    int ci = (wave * 4 + j) * 64 + lane;   // chunk index in tile
    int r  = ci >> 3;                      // local row 0..127
    int cs = (ci & 7) ^ (r & 7);           // swizzled source chunk
    int arow = bm + r; if (arow >= M) arow = M - 1;  // clamp; stores guarded
    aptr[j] = A  + (size_t)arow * K + cs * 8;
    bptr[j] = Bt + (size_t)(bn + r) * K + cs * 8;    // N % 128 == 0
    ldsoff[j] = (wave * 4 + j) * 64 * 8;   // ushort offset of chunk base
  }

  for (int k0 = 0; k0 < K; k0 += BKE) {
#pragma unroll
    for (int j = 0; j < 4; ++j) {
      gload_lds16(aptr[j] + k0, &As[ldsoff[j]]);
      gload_lds16(bptr[j] + k0, &Bs[ldsoff[j]]);
    }
    __syncthreads();   // drains vmcnt (global_load_lds) + lgkm
#pragma unroll
    for (int s = 0; s < 2; ++s) {
      short8 af[4], bf[4];
#pragma unroll
      for (int mt = 0; mt < 4; ++mt) {
        int mrow = wm * 64 + mt * 16 + l15;
        int sw = (s * 4 + quad) ^ (mrow & 7);
        af[mt] = *(const short8*)&As[(mrow * 8 + sw) * 8];
      }
#pragma unroll
      for (int nt = 0; nt < 4; ++nt) {
        int nrow = wn * 64 + nt * 16 + l15;
        int sw = (s * 4 + quad) ^ (nrow & 7);
        bf[nt] = *(const short8*)&Bs[(nrow * 8 + sw) * 8];
      }
#pragma unroll
      for (int mt = 0; mt < 4; ++mt)
#pragma unroll
        for (int nt = 0; nt < 4; ++nt)
          acc[mt][nt] = __builtin_amdgcn_mfma_f32_16x16x32_bf16(
              af[mt], bf[nt], acc[mt][nt], 0, 0, 0);
    }
    __syncthreads();
  }

  // epilogue: C/D layout col=lane&15, row=quad*4+i  (m89/m91-verified)
#pragma unroll
  for (int mt = 0; mt < 4; ++mt) {
#pragma unroll
    for (int nt = 0; nt < 4; ++nt) {
      const int col = bn + wn * 64 + nt * 16 + l15;
#pragma unroll
      for (int i = 0; i < 4; ++i) {
        const int row = bm + wm * 64 + mt * 16 + quad * 4 + i;
        if (row < M) C[(size_t)row * N + col] = rnbf(acc[mt][nt][i]);
      }
    }
  }
}

// ----------------------------- casts ---------------------------------------
__global__ __launch_bounds__(256) void cast_f32_to_bf16(
    const float* __restrict__ in, unsigned short* __restrict__ out,
    long long n4) {
  long long i = (long long)blockIdx.x * 256 + threadIdx.x;
  if (i >= n4) return;
  float4 v = ((const float4*)in)[i];
  ushort4 o;
  o.x = rnbf(v.x); o.y = rnbf(v.y); o.z = rnbf(v.z); o.w = rnbf(v.w);
  ((ushort4*)out)[i] = o;
}

// in [K][N] f32 -> out [N][K] bf16; K,N multiples of 32
__global__ __launch_bounds__(256) void transpose_cast_bf16(
    const float* __restrict__ in, unsigned short* __restrict__ out,
    int K, int N) {
  __shared__ float t[32][33];
  const int bx = blockIdx.x * 32;  // n
  const int by = blockIdx.y * 32;  // k
  const int tx = threadIdx.x & 31, ty = threadIdx.x >> 5;
#pragma unroll
  for (int j = 0; j < 4; ++j)
    t[ty + j * 8][tx] = in[(size_t)(by + ty + j * 8) * N + bx + tx];
  __syncthreads();
#pragma unroll
  for (int j = 0; j < 4; ++j)
    out[(size_t)(bx + ty + j * 8) * K + by + tx] = rnbf(t[tx][ty + j * 8]);
}

// ----------------------- CSR build (unchanged) -----------------------------
__global__ __launch_bounds__(256) void hist_dst(
    const int* __restrict__ dst, int* __restrict__ cnt, int E) {
  int e = blockIdx.x * blockDim.x + threadIdx.x;
  if (e < E) atomicAdd(&cnt[dst[e]], 1);
}

__global__ __launch_bounds__(1024) void scan_csr(
    int* __restrict__ cursor, int* __restrict__ rowptr, int n) {
  __shared__ int sm[1024];
  __shared__ int carry_s;
  const int t = threadIdx.x;
  if (t == 0) carry_s = 0;
  __syncthreads();
  for (int base = 0; base < n; base += 1024) {
    const int i = base + t;
    const int v = (i < n) ? cursor[i] : 0;
    sm[t] = v;
    __syncthreads();
    int x = v;
#pragma unroll
    for (int off = 1; off < 1024; off <<= 1) {
      int y = (t >= off) ? sm[t - off] : 0;
      __syncthreads();
      x += y;
      sm[t] = x;
      __syncthreads();
    }
    const int carry = carry_s;
    if (i < n) {
      rowptr[i + 1] = carry + x;
      cursor[i] = carry + x - v;
    }
    __syncthreads();
    if (t == 1023) carry_s = carry + x;
    __syncthreads();
  }
  if (t == 0) rowptr[0] = 0;
}

__global__ __launch_bounds__(256) void fill_csr(
    const int* __restrict__ dst, int* __restrict__ cursor,
    int* __restrict__ eid, int E) {
  int e = blockIdx.x * blockDim.x + threadIdx.x;
  if (e < E) {
    int pos = atomicAdd(&cursor[dst[e]], 1);
    eid[pos] = e;
  }
}

// ------- gather layer1: bf16 S [Nn,512] -> bf16 out (bias+relu fused) -------
__global__ __launch_bounds__(256) void gather1_b2b(
    const unsigned short* __restrict__ S, const int* __restrict__ src,
    const float* __restrict__ w, const int* __restrict__ rowptr,
    const int* __restrict__ eid, const float* __restrict__ bias,
    unsigned short* __restrict__ out, int Nn) {
  const int tn = threadIdx.x & 63;                 // 64 thr/node, 8 bf16 each
  const int node = blockIdx.x * 4 + (threadIdx.x >> 6);
  if (node >= Nn) return;
  const int f = tn << 3;
  float acc[8] = {};
  const int beg = rowptr[node], end = rowptr[node + 1];
  for (int i = beg; i < end; ++i) {
    const int e = eid[i];
    const int sv = src[e];
    const float ww = w[e];
    const uint4 u = *(const uint4*)(S + (size_t)sv * 512 + f);
    acc[0] = fmaf(bflo(u.x), ww, acc[0]);
    acc[1] = fmaf(bfhi(u.x), ww, acc[1]);
    acc[2] = fmaf(bflo(u.y), ww, acc[2]);
    acc[3] = fmaf(bfhi(u.y), ww, acc[3]);
    acc[4] = fmaf(bflo(u.z), ww, acc[4]);
    acc[5] = fmaf(bfhi(u.z), ww, acc[5]);
    acc[6] = fmaf(bflo(u.w), ww, acc[6]);
    acc[7] = fmaf(bfhi(u.w), ww, acc[7]);
  }
  float r[8];
#pragma unroll
  for (int j = 0; j < 8; ++j) r[j] = fmaxf(acc[j] + bias[f + j], 0.f);
  uint4 o;
  o.x = (unsigned int)rnbf(r[0]) | ((unsigned int)rnbf(r[1]) << 16);
  o.y = (unsigned int)rnbf(r[2]) | ((unsigned int)rnbf(r[3]) << 16);
  o.z = (unsigned int)rnbf(r[4]) | ((unsigned int)rnbf(r[5]) << 16);
  o.w = (unsigned int)rnbf(r[6]) | ((unsigned int)rnbf(r[7]) << 16);
  *(uint4*)(out + (size_t)node * 512 + f) = o;
}

// ------- gather layer2: bf16 S [Nn,256] -> f32 out (bias+relu fused) --------
__global__ __launch_bounds__(256) void gather2_b2f(
    const unsigned short* __restrict__ S, const int* __restrict__ src,
    const float* __restrict__ w, const int* __restrict__ rowptr,
    const int* __restrict__ eid, const float* __restrict__ bias,
    float* __restrict__ out, int Nn) {
  const int tn = threadIdx.x & 31;                 // 32 thr/node, 8 bf16 each
  const int node = blockIdx.x * 8 + (threadIdx.x >> 5);
  if (node >= Nn) return;
  const int f = tn << 3;
  float acc[8] = {};
  const int beg = rowptr[node], end = rowptr[node + 1];
  for (int i = beg; i < end; ++i) {
    const int e = eid[i];
    const int sv = src[e];
    const float ww = w[e];
    const uint4 u = *(const uint4*)(S + (size_t)sv * 256 + f);
    acc[0] = fmaf(bflo(u.x), ww, acc[0]);
    acc[1] = fmaf(bfhi(u.x), ww, acc[1]);
    acc[2] = fmaf(bflo(u.y), ww, acc[2]);
    acc[3] = fmaf(bfhi(u.y), ww, acc[3]);
    acc[4] = fmaf(bflo(u.z), ww, acc[4]);
    acc[5] = fmaf(bfhi(u.z), ww, acc[5]);
    acc[6] = fmaf(bflo(u.w), ww, acc[6]);
    acc[7] = fmaf(bfhi(u.w), ww, acc[7]);
  }
  float4 o1, o2;
  o1.x = fmaxf(acc[0] + bias[f + 0], 0.f);
  o1.y = fmaxf(acc[1] + bias[f + 1], 0.f);
  o1.z = fmaxf(acc[2] + bias[f + 2], 0.f);
  o1.w = fmaxf(acc[3] + bias[f + 3], 0.f);
  o2.x = fmaxf(acc[4] + bias[f + 4], 0.f);
  o2.y = fmaxf(acc[5] + bias[f + 5], 0.f);
  o2.z = fmaxf(acc[6] + bias[f + 6], 0.f);
  o2.w = fmaxf(acc[7] + bias[f + 7], 0.f);
  *(float4*)(out + (size_t)node * 256 + f) = o1;
  *(float4*)(out + (size_t)node * 256 + f + 4) = o2;
}

// ============================================================================
extern "C" void kernel_launch(void* const* d_in, const int* in_sizes, int n_in,
                              void* d_out, int out_size, void* d_ws, size_t ws_size,
                              hipStream_t stream) {
  const float* x  = (const float*)d_in[0];
  const int*   ei = (const int*)d_in[1];
  const float* ew = (const float*)d_in[2];
  const float* W1 = (const float*)d_in[3];
  const float* b1 = (const float*)d_in[4];
  const float* W2 = (const float*)d_in[5];
  const float* b2 = (const float*)d_in[6];

  const int D_IN = 1024, D_HID = 512, D_LAT = 256;
  const int Nn = in_sizes[0] / D_IN;   // 50000
  const int E  = in_sizes[2];          // 400000
  const int* src  = ei;
  const int* dstp = ei + E;

  // ws layout (region A aliases xb->hb, region B aliases s1->s2):
  //  A: [0, Nn*1024*2)            xb bf16; later hb bf16 (Nn*512*2 <= that)
  //  B: [A, A + Nn*512*2)         s1 bf16; later s2 bf16 (Nn*256*2 <= that)
  //  C: W1t, W2t, rowptr, cursor, eid                  (~3.3 MB)
  char* base = (char*)d_ws;
  const size_t szA = (size_t)Nn * D_IN * 2;
  const size_t szB = (size_t)Nn * D_HID * 2;
  unsigned short* xb  = (unsigned short*)base;
  unsigned short* hb  = (unsigned short*)base;             // alias, xb dead
  unsigned short* s1  = (unsigned short*)(base + szA);
  unsigned short* s2  = (unsigned short*)(base + szA);     // alias, s1 dead
  char* tail = base + szA + szB;
  unsigned short* W1t = (unsigned short*)tail;
  unsigned short* W2t = (unsigned short*)(tail + (size_t)D_IN * D_HID * 2);
  int* rowptr = (int*)(tail + (size_t)D_IN * D_HID * 2 + (size_t)D_HID * D_LAT * 2);
  int* cursor = rowptr + (Nn + 1);
  int* eid    = cursor + Nn;

  // ---- CSR build ----
  hipMemsetAsync(cursor, 0, (size_t)Nn * sizeof(int), stream);
  hist_dst<<<(E + 255) / 256, 256, 0, stream>>>(dstp, cursor, E);
  scan_csr<<<1, 1024, 0, stream>>>(cursor, rowptr, Nn);
  fill_csr<<<(E + 255) / 256, 256, 0, stream>>>(dstp, cursor, eid, E);

  // ---- casts ----
  long long n4 = (long long)Nn * D_IN / 4;
  cast_f32_to_bf16<<<(int)((n4 + 255) / 256), 256, 0, stream>>>(x, xb, n4);
  transpose_cast_bf16<<<dim3(D_HID / 32, D_IN / 32), 256, 0, stream>>>(
      W1, W1t, D_IN, D_HID);
  transpose_cast_bf16<<<dim3(D_LAT / 32, D_HID / 32), 256, 0, stream>>>(
      W2, W2t, D_HID, D_LAT);

  // ---- layer 1 ----
  dim3 g1(D_HID / TN, (Nn + TM - 1) / TM);
  gemm_bf16<<<g1, 256, 0, stream>>>(xb, W1t, s1, Nn, D_HID, D_IN);
  gather1_b2b<<<(Nn + 3) / 4, 256, 0, stream>>>(
      s1, src, ew, rowptr, eid, b1, hb, Nn);

  // ---- layer 2 ----
  dim3 g2(D_LAT / TN, (Nn + TM - 1) / TM);
  gemm_bf16<<<g2, 256, 0, stream>>>(hb, W2t, s2, Nn, D_LAT, D_HID);
  gather2_b2f<<<(Nn + 7) / 8, 256, 0, stream>>>(
      s2, src, ew, rowptr, eid, b2, (float*)d_out, Nn);
}